// Round 12
// baseline (83.154 us; speedup 1.0000x reference)
//
#include <hip/hip_runtime.h>
#include <hip/hip_bf16.h>

typedef __attribute__((ext_vector_type(8))) short short8;   // bf16x8 MFMA frag
typedef __attribute__((ext_vector_type(4))) float f32x4;
typedef __attribute__((ext_vector_type(4))) unsigned uint4v;

constexpr int N1 = 16384, N2 = 8192, N3 = 4096;
constexpr int WN = 36864;
constexpr float ISQ3 = 0.57735026918962576451f;

__device__ __forceinline__ unsigned short f2bf(float f) {
  unsigned u = __builtin_bit_cast(unsigned, f);
  u += 0x7fffu + ((u >> 16) & 1u);   // RNE
  return (unsigned short)(u >> 16);
}

__device__ __forceinline__ unsigned pkbf(float a, float b) {
  unsigned r;
  asm("v_cvt_pk_bf16_f32 %0, %1, %2" : "=v"(r) : "v"(a), "v"(b));
  return r;
}

#define MFMA(a, b, c) __builtin_amdgcn_mfma_f32_16x16x32_bf16((a), (b), (c), 0, 0, 0)
#define NTL(p) __builtin_nontemporal_load(p)

// two f32x4 -> one bf16x8 frag
#define CVT8(X0, X1, G) do { uint4v w_;                                       \
    w_[0] = pkbf(X0[0], X0[1]); w_[1] = pkbf(X0[2], X0[3]);                   \
    w_[2] = pkbf(X1[0], X1[1]); w_[3] = pkbf(X1[2], X1[3]);                   \
    G = __builtin_bit_cast(short8, w_); } while (0)

// H frag loader: rows e0+16*EF+nl, k = grp*8.. (kh0) and 32+grp*8.. (kh1)
#define LOADH(EF, LO, HI) do {                                                \
    const float* hp_ = H + (size_t)(e0 + 16 * (EF) + nl) * 64 + grp * 8;      \
    f32x4 x0_ = *(const f32x4*)hp_,        x1_ = *(const f32x4*)(hp_ + 4);    \
    f32x4 x2_ = *(const f32x4*)(hp_ + 32), x3_ = *(const f32x4*)(hp_ + 36);   \
    CVT8(x0_, x1_, LO); CVT8(x2_, x3_, HI); } while (0)

// ---------------- prep: [0,288) W2->Bp (LDS transpose, coalesced) | [288,1312) MLP | [1312,1440) scales
__global__ __launch_bounds__(256)
void k_prep(const float* __restrict__ wgt, const float* __restrict__ W0,
            const float* __restrict__ b0, const float* __restrict__ W1,
            const float* __restrict__ b1, const float* __restrict__ W2,
            const float* __restrict__ d1, const float* __restrict__ d2,
            float* __restrict__ H, unsigned short* __restrict__ Bp,
            float* __restrict__ sBg, float* __restrict__ sDg,
            float* __restrict__ sCg, float* __restrict__ d2T) {
  __shared__ __align__(16) float shm[10400];
  const int bid = blockIdx.x;
  const int tid = threadIdx.x;

  if (bid < 288) {
    // ---- W2 -> Bp: block handles n-chunk [n0, n0+128), all 64 k-rows.
    const int n0 = bid * 128;
#pragma unroll
    for (int q = 0; q < 8; ++q) {
      const int flat = tid + q * 256;       // f32x4 units, 0..2047
      const int row = flat >> 5, c4 = flat & 31;
      *(f32x4*)&shm[row * 132 + c4 * 4] =
          *(const f32x4*)(W2 + (size_t)row * WN + n0 + c4 * 4);
    }
    __syncthreads();
#pragma unroll
    for (int q = 0; q < 4; ++q) {
      const int p = tid + q * 256;          // 0..1023
      const int ntl = p >> 7, kh = (p >> 6) & 1, lane2 = p & 63;
      const int k0 = kh * 32 + (lane2 >> 4) * 8;
      const int col = ntl * 16 + (lane2 & 15);
      short8 v;
#pragma unroll
      for (int qq = 0; qq < 8; ++qq) v[qq] = (short)f2bf(shm[(k0 + qq) * 132 + col]);
      *(short8*)(Bp + ((size_t)(n0 * 8 + p)) * 8) = v;
    }
  } else if (bid < 1312) {
    // ---- MLP: H = relu(relu(weight@W0+b0)@W1+b1)
    float* h0s = shm;
    const int r = tid >> 6, jj = tid & 63;
    const int e = (bid - 288) * 4 + r;
    float a = b0[jj];
#pragma unroll
    for (int i = 0; i < 16; ++i) a = fmaf(wgt[e * 16 + i], W0[i * 64 + jj], a);
    h0s[r * 64 + jj] = fmaxf(a, 0.f);
    __syncthreads();
    float a1 = b1[jj];
#pragma unroll
    for (int i = 0; i < 64; ++i) a1 = fmaf(h0s[r * 64 + i], W1[i * 64 + jj], a1);
    H[e * 64 + jj] = fmaxf(a1, 0.f);
  } else {
    // ---- scales: sBg[u][e]=s1, sDg[u][e]=ISQ3*dot12, sCg[3u+i][e]=v1_i*s2, d2T[c][e]
    float* d1s = shm;            // [32][321]
    float* d2s = shm + 10272;    // [32][4]
    const int e0 = (bid - 1312) * 32;
    for (int x = tid; x < 32 * 320; x += 256) {
      int e = x / 320, c = x % 320;
      d1s[e * 321 + c] = d1[(size_t)(e0 + e) * 320 + c];
    }
    if (tid < 128) d2s[tid] = d2[(size_t)e0 * 4 + tid];
    __syncthreads();
    const int e = tid & 31;
    const float s2 = d2s[e * 4 + 0];
    const float w1 = d2s[e * 4 + 1], w2 = d2s[e * 4 + 2], w3 = d2s[e * 4 + 3];
    for (int row = 128 + (tid >> 5); row < 516; row += 8) {
      float v; float* dst;
      if (row < 256)      { v = d1s[e * 321 + (row - 128)];            dst = sBg + (size_t)(row - 128) * 4096; }
      else if (row < 320) { int u = row - 256;
        v = ISQ3 * (d1s[e * 321 + 128 + 3 * u] * w1 + d1s[e * 321 + 129 + 3 * u] * w2 +
                    d1s[e * 321 + 130 + 3 * u] * w3);                  dst = sDg + (size_t)u * 4096; }
      else if (row < 512) { v = d1s[e * 321 + 128 + (row - 320)] * s2; dst = sCg + (size_t)(row - 320) * 4096; }
      else                { v = d2s[e * 4 + (row - 512)];              dst = d2T + (size_t)(row - 512) * 4096; }
      dst[e0 + e] = v;
    }
  }
}

// ---------------- k_main: exclusive-writer columns, b2 via MFMA C-init, depth-3 rings,
// NON-TEMPORAL scale/b2/out traffic (protect per-XCD L2 residency of Bp slices) ----------------
// bid [0,512): AD — e-tile 64, j = bid&7 (XCD-pinned). Writes out0 cols [16j,16j+16).
// bid [512,1024): BC — e-tile 32, jc = xcd&3. Writes out1 w1 cols [16jc,16jc+16) (x3 i).
__global__ __launch_bounds__(256, 3)
void k_main(const float* __restrict__ sBg, const float* __restrict__ sDg,
            const float* __restrict__ sCg, const float* __restrict__ d2T,
            const float* __restrict__ H, const unsigned short* __restrict__ Bp,
            const float* __restrict__ b2, const float* __restrict__ bias,
            float* __restrict__ out) {
  __shared__ __align__(16) float buf[8448];   // 33.8 KB: AD [4][64][33], BC [4][32][65]
  const int bid = blockIdx.x, tid = threadIdx.x;
  const int wid = tid >> 6, lane = tid & 63;
  const int nl = lane & 15, grp = lane >> 4;
  const short8* Bp8 = (const short8*)Bp;
  const f32x4 Zv = {0.f, 0.f, 0.f, 0.f};

  if (bid < 512) {
    // ================= AD =================
    const int j = bid & 7;
    const int e0 = (bid >> 3) * 64;
    short8 hL0, hH0, hL1, hH1, hL2, hH2, hL3, hH3;
    LOADH(0, hL0, hH0);
    LOADH(1, hL1, hH1);
    LOADH(2, hL2, hH2);
    LOADH(3, hL3, hH3);

    f32x4 aA0 = Zv, aA1 = Zv, aA2 = Zv, aA3 = Zv;
    f32x4 aD0 = Zv, aD1 = Zv, aD2 = Zv, aD3 = Zv;

    {   // phase A: u in [wid*32, +32), nt = u*8 + j
      const int u0 = wid * 32;
      const short8* pa = Bp8 + (size_t)(u0 * 8 + j) * 128 + lane;
      const float* sb = sBg + (size_t)u0 * 4096 + e0 + nl;
      const float* pb = b2 + (size_t)u0 * 128 + 16 * j + 4 * grp;
      short8 Fa[3], Fb[3]; f32x4 Bv[3];
      float S0[3], S1[3], S2[3], S3[3];
#pragma unroll
      for (int q = 0; q < 3; ++q) {
        Fa[q] = pa[0]; Fb[q] = pa[64];
        Bv[q] = NTL((const f32x4*)pb);
        S0[q] = NTL(sb); S1[q] = NTL(sb + 16); S2[q] = NTL(sb + 32); S3[q] = NTL(sb + 48);
        pa += 1024; sb += 4096; pb += 128;
      }
#pragma unroll
      for (int t = 0; t < 32; ++t) {
        const int s = t % 3;
        short8 f0 = Fa[s], f1 = Fb[s]; f32x4 b = Bv[s];
        float c0 = S0[s], c1 = S1[s], c2 = S2[s], c3 = S3[s];
        if (t < 29) {
          Fa[s] = pa[0]; Fb[s] = pa[64];
          Bv[s] = NTL((const f32x4*)pb);
          S0[s] = NTL(sb); S1[s] = NTL(sb + 16); S2[s] = NTL(sb + 32); S3[s] = NTL(sb + 48);
          pa += 1024; sb += 4096; pb += 128;
        }
        f32x4 tt;
        tt = MFMA(f0, hL0, b); tt = MFMA(f1, hH0, tt); aA0 += c0 * tt;
        tt = MFMA(f0, hL1, b); tt = MFMA(f1, hH1, tt); aA1 += c1 * tt;
        tt = MFMA(f0, hL2, b); tt = MFMA(f1, hH2, tt); aA2 += c2 * tt;
        tt = MFMA(f0, hL3, b); tt = MFMA(f1, hH3, tt); aA3 += c3 * tt;
      }
    }
    {   // phase D: u in [wid*16, +16), nt = 1792 + u*8 + j
      const int u0 = wid * 16;
      const short8* pa = Bp8 + (size_t)(1792 + u0 * 8 + j) * 128 + lane;
      const float* sd = sDg + (size_t)u0 * 4096 + e0 + nl;
      const float* pb = b2 + (size_t)(N1 + N2 + N3) + (size_t)u0 * 128 + 16 * j + 4 * grp;
      short8 Fa[3], Fb[3]; f32x4 Bv[3];
      float S0[3], S1[3], S2[3], S3[3];
#pragma unroll
      for (int q = 0; q < 3; ++q) {
        Fa[q] = pa[0]; Fb[q] = pa[64];
        Bv[q] = NTL((const f32x4*)pb);
        S0[q] = NTL(sd); S1[q] = NTL(sd + 16); S2[q] = NTL(sd + 32); S3[q] = NTL(sd + 48);
        pa += 1024; sd += 4096; pb += 128;
      }
#pragma unroll
      for (int t = 0; t < 16; ++t) {
        const int s = t % 3;
        short8 f0 = Fa[s], f1 = Fb[s]; f32x4 b = Bv[s];
        float c0 = S0[s], c1 = S1[s], c2 = S2[s], c3 = S3[s];
        if (t < 13) {
          Fa[s] = pa[0]; Fb[s] = pa[64];
          Bv[s] = NTL((const f32x4*)pb);
          S0[s] = NTL(sd); S1[s] = NTL(sd + 16); S2[s] = NTL(sd + 32); S3[s] = NTL(sd + 48);
          pa += 1024; sd += 4096; pb += 128;
        }
        f32x4 tt;
        tt = MFMA(f0, hL0, b); tt = MFMA(f1, hH0, tt); aD0 += c0 * tt;
        tt = MFMA(f0, hL1, b); tt = MFMA(f1, hH1, tt); aD1 += c1 * tt;
        tt = MFMA(f0, hL2, b); tt = MFMA(f1, hH2, tt); aD2 += c2 * tt;
        tt = MFMA(f0, hL3, b); tt = MFMA(f1, hH3, tt); aD3 += c3 * tt;
      }
    }
    // epilogue: 4-wave store, sum, direct write (exclusive writer)
    {
      float* bw = &buf[wid * 2112];
#pragma unroll
      for (int r = 0; r < 4; ++r) {
        bw[nl * 33 + grp * 4 + r]             = aA0[r];
        bw[(16 + nl) * 33 + grp * 4 + r]      = aA1[r];
        bw[(32 + nl) * 33 + grp * 4 + r]      = aA2[r];
        bw[(48 + nl) * 33 + grp * 4 + r]      = aA3[r];
        bw[nl * 33 + 16 + grp * 4 + r]        = aD0[r];
        bw[(16 + nl) * 33 + 16 + grp * 4 + r] = aD1[r];
        bw[(32 + nl) * 33 + 16 + grp * 4 + r] = aD2[r];
        bw[(48 + nl) * 33 + 16 + grp * 4 + r] = aD3[r];
      }
      __syncthreads();
#pragma unroll
      for (int it = 0; it < 4; ++it) {
        const int p = tid + it * 256;
        const int e = p >> 4, w = p & 15;
        float ta = buf[e * 33 + w] + buf[2112 + e * 33 + w] +
                   buf[4224 + e * 33 + w] + buf[6336 + e * 33 + w];
        float td = buf[e * 33 + 16 + w] + buf[2112 + e * 33 + 16 + w] +
                   buf[4224 + e * 33 + 16 + w] + buf[6336 + e * 33 + 16 + w];
        const float s2v = NTL(&d2T[e0 + e]);
        const float bw2 = NTL(&bias[16 * j + w]);
        __builtin_nontemporal_store(s2v * ta + td + bw2,
                                    &out[(size_t)(e0 + e) * 320 + 16 * j + w]);
      }
    }
  } else {
    // ================= BC =================
    const int idx = bid - 512;
    const int xcd = idx & 7;
    const int jc = xcd & 3;
    const int tile = ((idx >> 3) << 1) | (xcd >> 2);
    const int e0 = tile * 32;
    short8 gL0, gH0, gL1, gH1;
    LOADH(0, gL0, gH0);
    LOADH(1, gL1, gH1);

    f32x4 aB0 = Zv, aB1 = Zv;
    f32x4 c00 = Zv, c01 = Zv, c02 = Zv, c10 = Zv, c11 = Zv, c12 = Zv;

    {   // phase B: u in [wid*32,+32), nt = 1024 + u*4 + jc
      const int u0 = wid * 32;
      const short8* pa = Bp8 + (size_t)(1024 + u0 * 4 + jc) * 128 + lane;
      const float* sb = sBg + (size_t)u0 * 4096 + e0 + nl;
      const float* pb = b2 + (size_t)N1 + (size_t)u0 * 64 + 16 * jc + 4 * grp;
      short8 Fa[3], Fb[3]; f32x4 Bv[3];
      float S0[3], S1[3];
#pragma unroll
      for (int q = 0; q < 3; ++q) {
        Fa[q] = pa[0]; Fb[q] = pa[64];
        Bv[q] = NTL((const f32x4*)pb);
        S0[q] = NTL(sb); S1[q] = NTL(sb + 16);
        pa += 512; sb += 4096; pb += 64;
      }
#pragma unroll
      for (int t = 0; t < 32; ++t) {
        const int s = t % 3;
        short8 f0 = Fa[s], f1 = Fb[s]; f32x4 b = Bv[s];
        float c0 = S0[s], c1 = S1[s];
        if (t < 29) {
          Fa[s] = pa[0]; Fb[s] = pa[64];
          Bv[s] = NTL((const f32x4*)pb);
          S0[s] = NTL(sb); S1[s] = NTL(sb + 16);
          pa += 512; sb += 4096; pb += 64;
        }
        f32x4 tt;
        tt = MFMA(f0, gL0, b); tt = MFMA(f1, gH0, tt); aB0 += c0 * tt;
        tt = MFMA(f0, gL1, b); tt = MFMA(f1, gH1, tt); aB1 += c1 * tt;
      }
    }
    {   // phase C: u in [wid*16,+16), nt = 1536 + u*4 + jc
      const int u0 = wid * 16;
      const short8* pa = Bp8 + (size_t)(1536 + u0 * 4 + jc) * 128 + lane;
      const float* sc = sCg + (size_t)(3 * u0) * 4096 + e0 + nl;
      const float* pb = b2 + (size_t)(N1 + N2) + (size_t)u0 * 64 + 16 * jc + 4 * grp;
      short8 Fa[3], Fb[3]; f32x4 Bv[3];
      float S00[3], S01[3], S10[3], S11[3], S20[3], S21[3];
#pragma unroll
      for (int q = 0; q < 3; ++q) {
        Fa[q] = pa[0]; Fb[q] = pa[64];
        Bv[q] = NTL((const f32x4*)pb);
        S00[q] = NTL(sc); S01[q] = NTL(sc + 16);
        S10[q] = NTL(sc + 4096); S11[q] = NTL(sc + 4096 + 16);
        S20[q] = NTL(sc + 8192); S21[q] = NTL(sc + 8192 + 16);
        pa += 512; sc += 12288; pb += 64;
      }
#pragma unroll
      for (int t = 0; t < 16; ++t) {
        const int s = t % 3;
        short8 f0 = Fa[s], f1 = Fb[s]; f32x4 b = Bv[s];
        float d00 = S00[s], d01 = S01[s], d10 = S10[s], d11 = S11[s], d20 = S20[s], d21 = S21[s];
        if (t < 13) {
          Fa[s] = pa[0]; Fb[s] = pa[64];
          Bv[s] = NTL((const f32x4*)pb);
          S00[s] = NTL(sc); S01[s] = NTL(sc + 16);
          S10[s] = NTL(sc + 4096); S11[s] = NTL(sc + 4096 + 16);
          S20[s] = NTL(sc + 8192); S21[s] = NTL(sc + 8192 + 16);
          pa += 512; sc += 12288; pb += 64;
        }
        f32x4 t0 = MFMA(f0, gL0, b); t0 = MFMA(f1, gH0, t0);
        f32x4 t1 = MFMA(f0, gL1, b); t1 = MFMA(f1, gH1, t1);
        c00 += d00 * t0; c01 += d10 * t0; c02 += d20 * t0;
        c10 += d01 * t1; c11 += d11 * t1; c12 += d21 * t1;
      }
    }
    // epilogue: 4-wave store, sum, direct write; slots {b, c0, c1, c2}
    {
      float* bw = &buf[wid * 2080];
#pragma unroll
      for (int r = 0; r < 4; ++r) {
        const int w1 = grp * 4 + r;
        bw[nl * 65 + w1]             = aB0[r];
        bw[(16 + nl) * 65 + w1]      = aB1[r];
        bw[nl * 65 + 16 + w1]        = c00[r];
        bw[nl * 65 + 32 + w1]        = c01[r];
        bw[nl * 65 + 48 + w1]        = c02[r];
        bw[(16 + nl) * 65 + 16 + w1] = c10[r];
        bw[(16 + nl) * 65 + 32 + w1] = c11[r];
        bw[(16 + nl) * 65 + 48 + w1] = c12[r];
      }
      __syncthreads();
#pragma unroll
      for (int it = 0; it < 6; ++it) {
        const int p = tid + it * 256;
        const int e = p / 48, rem = p % 48;
        const int w1 = rem / 3, i = rem % 3;
        float tb = buf[e * 65 + w1] + buf[2080 + e * 65 + w1] +
                   buf[4160 + e * 65 + w1] + buf[6240 + e * 65 + w1];
        const int co = 16 + i * 16 + w1;
        float tc = buf[e * 65 + co] + buf[2080 + e * 65 + co] +
                   buf[4160 + e * 65 + co] + buf[6240 + e * 65 + co];
        const float v2 = NTL(&d2T[(1 + i) * 4096 + e0 + e]);
        __builtin_nontemporal_store(tb * v2 + tc,
            &out[(size_t)(e0 + e) * 320 + 128 + (size_t)(16 * jc + w1) * 3 + i]);
      }
    }
  }
}

extern "C" void kernel_launch(void* const* d_in, const int* in_sizes, int n_in,
                              void* d_out, int out_size, void* d_ws, size_t ws_size,
                              hipStream_t stream) {
  const float* d1   = (const float*)d_in[0];
  const float* d2   = (const float*)d_in[1];
  const float* wgt  = (const float*)d_in[2];
  const float* W0   = (const float*)d_in[3];
  const float* b0   = (const float*)d_in[4];
  const float* W1   = (const float*)d_in[5];
  const float* b1   = (const float*)d_in[6];
  const float* W2   = (const float*)d_in[7];
  const float* b2   = (const float*)d_in[8];
  const float* bias = (const float*)d_in[9];
  float* out = (float*)d_out;

  char* ws = (char*)d_ws;
  float* H           = (float*)(ws);                         // 1 MiB
  unsigned short* Bp = (unsigned short*)(ws + (1u << 20));   // 4.72 MB
  float* sBg         = (float*)(ws + (8u << 20));            // 2 MB  [128][4096] s1
  float* sDg         = (float*)(ws + (10u << 20));           // 1 MB  [64][4096]  ISQ3*dot12
  float* sCg         = (float*)(ws + (11u << 20));           // 3 MB  [192][4096] v1_i*s2
  float* d2T         = (float*)(ws + (14u << 20));           // 64 KB [4][4096]

  k_prep<<<1440, 256, 0, stream>>>(wgt, W0, b0, W1, b1, W2, d1, d2,
                                   H, Bp, sBg, sDg, sCg, d2T);
  k_main<<<1024, 256, 0, stream>>>(sBg, sDg, sCg, d2T, H, Bp, b2, bias, out);
}

// Round 14
// 72.562 us; speedup vs baseline: 1.1460x; 1.1460x over previous
//
#include <hip/hip_runtime.h>
#include <hip/hip_bf16.h>

typedef __attribute__((ext_vector_type(8))) short short8;   // bf16x8 MFMA frag
typedef __attribute__((ext_vector_type(4))) float f32x4;
typedef __attribute__((ext_vector_type(4))) unsigned uint4v;

#define GAS __attribute__((address_space(1)))
#define LAS __attribute__((address_space(3)))

constexpr int N1 = 16384, N2 = 8192, N3 = 4096;
constexpr int WN = 36864;
constexpr float ISQ3 = 0.57735026918962576451f;

__device__ __forceinline__ unsigned short f2bf(float f) {
  unsigned u = __builtin_bit_cast(unsigned, f);
  u += 0x7fffu + ((u >> 16) & 1u);   // RNE
  return (unsigned short)(u >> 16);
}
__device__ __forceinline__ unsigned pkbf(float a, float b) {
  unsigned r;
  asm("v_cvt_pk_bf16_f32 %0, %1, %2" : "=v"(r) : "v"(a), "v"(b));
  return r;
}
__device__ __forceinline__ float bf2f(unsigned short h) {
  return __builtin_bit_cast(float, (unsigned)h << 16);
}
__device__ __forceinline__ void glds16(const void* g, void* l) {
  __builtin_amdgcn_global_load_lds((GAS const void*)g, (LAS void*)l, 16, 0, 0);
}

#define MFMA(a, b, c) __builtin_amdgcn_mfma_f32_16x16x32_bf16((a), (b), (c), 0, 0, 0)
#define WAITVM(N) asm volatile("s_waitcnt vmcnt(" #N ")" ::: "memory")

// two f32x4 -> one bf16x8 frag
#define CVT8(X0, X1, G) do { uint4v w_;                                       \
    w_[0] = pkbf(X0[0], X0[1]); w_[1] = pkbf(X0[2], X0[3]);                   \
    w_[2] = pkbf(X1[0], X1[1]); w_[3] = pkbf(X1[2], X1[3]);                   \
    G = __builtin_bit_cast(short8, w_); } while (0)

#define LOADH(EF, LO, HI) do {                                                \
    const float* hp_ = H + (size_t)(e0 + 16 * (EF) + nl) * 64 + grp * 8;      \
    f32x4 x0_ = *(const f32x4*)hp_,        x1_ = *(const f32x4*)(hp_ + 4);    \
    f32x4 x2_ = *(const f32x4*)(hp_ + 32), x3_ = *(const f32x4*)(hp_ + 36);   \
    CVT8(x0_, x1_, LO); CVT8(x2_, x3_, HI); } while (0)

// ---------------- prep: [0,288) W2->Bp (LDS transpose, coalesced) | [288,1312) MLP | [1312,1440) scales
__global__ __launch_bounds__(256)
void k_prep(const float* __restrict__ wgt, const float* __restrict__ W0,
            const float* __restrict__ b0, const float* __restrict__ W1,
            const float* __restrict__ b1, const float* __restrict__ W2,
            const float* __restrict__ d1, const float* __restrict__ d2,
            float* __restrict__ H, unsigned short* __restrict__ Bp,
            float* __restrict__ sBg, float* __restrict__ sDg,
            float* __restrict__ sCg, float* __restrict__ d2T) {
  __shared__ __align__(16) float shm[10400];
  const int bid = blockIdx.x;
  const int tid = threadIdx.x;

  if (bid < 288) {
    const int n0 = bid * 128;
#pragma unroll
    for (int q = 0; q < 8; ++q) {
      const int flat = tid + q * 256;
      const int row = flat >> 5, c4 = flat & 31;
      *(f32x4*)&shm[row * 132 + c4 * 4] =
          *(const f32x4*)(W2 + (size_t)row * WN + n0 + c4 * 4);
    }
    __syncthreads();
#pragma unroll
    for (int q = 0; q < 4; ++q) {
      const int p = tid + q * 256;
      const int ntl = p >> 7, kh = (p >> 6) & 1, lane2 = p & 63;
      const int k0 = kh * 32 + (lane2 >> 4) * 8;
      const int col = ntl * 16 + (lane2 & 15);
      short8 v;
#pragma unroll
      for (int qq = 0; qq < 8; ++qq) v[qq] = (short)f2bf(shm[(k0 + qq) * 132 + col]);
      *(short8*)(Bp + ((size_t)(n0 * 8 + p)) * 8) = v;
    }
  } else if (bid < 1312) {
    float* h0s = shm;
    const int r = tid >> 6, jj = tid & 63;
    const int e = (bid - 288) * 4 + r;
    float a = b0[jj];
#pragma unroll
    for (int i = 0; i < 16; ++i) a = fmaf(wgt[e * 16 + i], W0[i * 64 + jj], a);
    h0s[r * 64 + jj] = fmaxf(a, 0.f);
    __syncthreads();
    float a1 = b1[jj];
#pragma unroll
    for (int i = 0; i < 64; ++i) a1 = fmaf(h0s[r * 64 + i], W1[i * 64 + jj], a1);
    H[e * 64 + jj] = fmaxf(a1, 0.f);
  } else {
    float* d1s = shm;            // [32][321]
    float* d2s = shm + 10272;    // [32][4]
    const int e0 = (bid - 1312) * 32;
    for (int x = tid; x < 32 * 320; x += 256) {
      int e = x / 320, c = x % 320;
      d1s[e * 321 + c] = d1[(size_t)(e0 + e) * 320 + c];
    }
    if (tid < 128) d2s[tid] = d2[(size_t)e0 * 4 + tid];
    __syncthreads();
    const int e = tid & 31;
    const float s2 = d2s[e * 4 + 0];
    const float w1 = d2s[e * 4 + 1], w2 = d2s[e * 4 + 2], w3 = d2s[e * 4 + 3];
    for (int row = 128 + (tid >> 5); row < 516; row += 8) {
      float v; float* dst;
      if (row < 256)      { v = d1s[e * 321 + (row - 128)];            dst = sBg + (size_t)(row - 128) * 4096; }
      else if (row < 320) { int u = row - 256;
        v = ISQ3 * (d1s[e * 321 + 128 + 3 * u] * w1 + d1s[e * 321 + 129 + 3 * u] * w2 +
                    d1s[e * 321 + 130 + 3 * u] * w3);                  dst = sDg + (size_t)u * 4096; }
      else if (row < 512) { v = d1s[e * 321 + 128 + (row - 320)] * s2; dst = sCg + (size_t)(row - 320) * 4096; }
      else                { v = d2s[e * 4 + (row - 512)];              dst = d2T + (size_t)(row - 512) * 4096; }
      dst[e0 + e] = v;
    }
  }
}

// ---------------- k_main: gl_lds 3-slot ring pipeline, LDS scales (bf16), exclusive-writer cols ----
// bid [0,512): AD — e-tile 64, j = bid&7. bid [512,1024): BC — e-tile 32, jc = xcd&3.
__global__ __launch_bounds__(256, 2)
void k_main(const float* __restrict__ sBg, const float* __restrict__ sDg,
            const float* __restrict__ sCg, const float* __restrict__ d2T,
            const float* __restrict__ H, const unsigned short* __restrict__ Bp,
            const float* __restrict__ b2, const float* __restrict__ bias,
            float* __restrict__ out) {
  __shared__ __align__(16) char smem[61440];
  const int bid = blockIdx.x, tid = threadIdx.x;
  const int wid = tid >> 6, lane = tid & 63;
  const int nl = lane & 15, grp = lane >> 4;
  const char* BpB = (const char*)Bp;
  const f32x4 Zv = {0.f, 0.f, 0.f, 0.f};

  if (bid < 512) {
    // ================= AD: smem = sB[128][64]bf16 | sD[64][64]bf16 | b2A[128][16]f32 | b2D[64][16]f32 | ring
    const int j = bid & 7;
    const int e0 = (bid >> 3) * 64;
    {
      unsigned* dA = (unsigned*)smem;                    // sB pairs [128][32]
      for (int x = tid; x < 4096; x += 256) {
        const float* s = sBg + (size_t)(x >> 5) * 4096 + e0 + (x & 31) * 2;
        dA[x] = pkbf(s[0], s[1]);
      }
      unsigned* dD = (unsigned*)(smem + 16384);          // sD pairs [64][32]
      for (int x = tid; x < 2048; x += 256) {
        const float* s = sDg + (size_t)(x >> 5) * 4096 + e0 + (x & 31) * 2;
        dD[x] = pkbf(s[0], s[1]);
      }
      float* bA = (float*)(smem + 24576);                // b2A [128][16]
      for (int x = tid; x < 2048; x += 256)
        bA[x] = b2[(size_t)(x >> 4) * 128 + 16 * j + (x & 15)];
      float* bD = (float*)(smem + 32768);                // b2D [64][16]
      for (int x = tid; x < 1024; x += 256)
        bD[x] = b2[(size_t)(N1 + N2 + N3) + (size_t)(x >> 4) * 128 + 16 * j + (x & 15)];
    }
    short8 hL0, hH0, hL1, hH1, hL2, hH2, hL3, hH3;
    LOADH(0, hL0, hH0);
    LOADH(1, hL1, hH1);
    LOADH(2, hL2, hH2);
    LOADH(3, hL3, hH3);
    __syncthreads();

    const int u0A = wid * 32, u0D = wid * 16;
    char* ring = smem + 36864 + wid * 6144;
    const char* gA = BpB + ((size_t)(u0A * 8 + j) * 128 + lane) * 16;
    const char* gD = BpB + ((size_t)(1792 + u0D * 8 + j) * 128 + lane) * 16;
    const unsigned short* sbA = (const unsigned short*)smem + (size_t)u0A * 64 + nl;
    const unsigned short* sdD = (const unsigned short*)(smem + 16384) + (size_t)u0D * 64 + nl;
    const float* bvA = (const float*)(smem + 24576) + (size_t)u0A * 16 + grp * 4;
    const float* bvD = (const float*)(smem + 32768) + (size_t)u0D * 16 + grp * 4;

    f32x4 aA0 = Zv, aA1 = Zv, aA2 = Zv, aA3 = Zv;
    f32x4 aD0 = Zv, aD1 = Zv, aD2 = Zv, aD3 = Zv;

#define STG_A(K) do { char* dd_ = ring + ((K) % 3) * 2048;                     \
      glds16(gA + (size_t)(K) * 16384, dd_);                                   \
      glds16(gA + (size_t)(K) * 16384 + 1024, dd_ + 1024); } while (0)
#define STG_D(K) do { char* dd_ = ring + ((2 + (K)) % 3) * 2048;               \
      glds16(gD + (size_t)(K) * 16384, dd_);                                   \
      glds16(gD + (size_t)(K) * 16384 + 1024, dd_ + 1024); } while (0)

    STG_A(0); STG_A(1);
#pragma unroll
    for (int t = 0; t < 32; ++t) {
      WAITVM(2);
      if (t < 30) STG_A(t + 2); else STG_D(t - 30);
      const char* rs = ring + (t % 3) * 2048;
      short8 f0 = *(const short8*)(rs + lane * 16);
      short8 f1 = *(const short8*)(rs + 1024 + lane * 16);
      float c0 = bf2f(sbA[t * 64]);
      float c1 = bf2f(sbA[t * 64 + 16]);
      float c2 = bf2f(sbA[t * 64 + 32]);
      float c3 = bf2f(sbA[t * 64 + 48]);
      f32x4 bv = *(const f32x4*)(bvA + t * 16);
      f32x4 tt;
      tt = MFMA(f0, hL0, bv); tt = MFMA(f1, hH0, tt); aA0 += c0 * tt;
      tt = MFMA(f0, hL1, bv); tt = MFMA(f1, hH1, tt); aA1 += c1 * tt;
      tt = MFMA(f0, hL2, bv); tt = MFMA(f1, hH2, tt); aA2 += c2 * tt;
      tt = MFMA(f0, hL3, bv); tt = MFMA(f1, hH3, tt); aA3 += c3 * tt;
    }
#pragma unroll
    for (int t = 0; t < 16; ++t) {
      if (t < 14)      { WAITVM(2); STG_D(t + 2); }
      else if (t == 14){ WAITVM(2); }
      else             { WAITVM(0); }
      const char* rs = ring + ((2 + t) % 3) * 2048;
      short8 f0 = *(const short8*)(rs + lane * 16);
      short8 f1 = *(const short8*)(rs + 1024 + lane * 16);
      float c0 = bf2f(sdD[t * 64]);
      float c1 = bf2f(sdD[t * 64 + 16]);
      float c2 = bf2f(sdD[t * 64 + 32]);
      float c3 = bf2f(sdD[t * 64 + 48]);
      f32x4 bv = *(const f32x4*)(bvD + t * 16);
      f32x4 tt;
      tt = MFMA(f0, hL0, bv); tt = MFMA(f1, hH0, tt); aD0 += c0 * tt;
      tt = MFMA(f0, hL1, bv); tt = MFMA(f1, hH1, tt); aD1 += c1 * tt;
      tt = MFMA(f0, hL2, bv); tt = MFMA(f1, hH2, tt); aD2 += c2 * tt;
      tt = MFMA(f0, hL3, bv); tt = MFMA(f1, hH3, tt); aD3 += c3 * tt;
    }
#undef STG_A
#undef STG_D
    __syncthreads();
    // epilogue: 4-wave reduce in LDS (alias), direct store
    float* buf = (float*)smem;
    {
      float* bw = buf + wid * 2112;
#pragma unroll
      for (int r = 0; r < 4; ++r) {
        bw[nl * 33 + grp * 4 + r]             = aA0[r];
        bw[(16 + nl) * 33 + grp * 4 + r]      = aA1[r];
        bw[(32 + nl) * 33 + grp * 4 + r]      = aA2[r];
        bw[(48 + nl) * 33 + grp * 4 + r]      = aA3[r];
        bw[nl * 33 + 16 + grp * 4 + r]        = aD0[r];
        bw[(16 + nl) * 33 + 16 + grp * 4 + r] = aD1[r];
        bw[(32 + nl) * 33 + 16 + grp * 4 + r] = aD2[r];
        bw[(48 + nl) * 33 + 16 + grp * 4 + r] = aD3[r];
      }
    }
    __syncthreads();
#pragma unroll
    for (int it = 0; it < 4; ++it) {
      const int p = tid + it * 256;
      const int e = p >> 4, w = p & 15;
      float ta = buf[e * 33 + w] + buf[2112 + e * 33 + w] +
                 buf[4224 + e * 33 + w] + buf[6336 + e * 33 + w];
      float td = buf[e * 33 + 16 + w] + buf[2112 + e * 33 + 16 + w] +
                 buf[4224 + e * 33 + 16 + w] + buf[6336 + e * 33 + 16 + w];
      out[(size_t)(e0 + e) * 320 + 16 * j + w] = d2T[e0 + e] * ta + td + bias[16 * j + w];
    }
  } else {
    // ================= BC: smem = sB[128][32]bf16 | sC[192][32]bf16 | b2B[128][16] | b2C[64][16] | ring
    const int idx = bid - 512;
    const int xcd = idx & 7;
    const int jc = xcd & 3;
    const int tile = ((idx >> 3) << 1) | (xcd >> 2);
    const int e0 = tile * 32;
    {
      unsigned* dB = (unsigned*)smem;                    // sB pairs [128][16]
      for (int x = tid; x < 2048; x += 256) {
        const float* s = sBg + (size_t)(x >> 4) * 4096 + e0 + (x & 15) * 2;
        dB[x] = pkbf(s[0], s[1]);
      }
      unsigned* dC = (unsigned*)(smem + 8192);           // sC pairs [192][16]
      for (int x = tid; x < 3072; x += 256) {
        const float* s = sCg + (size_t)(x >> 4) * 4096 + e0 + (x & 15) * 2;
        dC[x] = pkbf(s[0], s[1]);
      }
      float* bB = (float*)(smem + 20480);                // b2B [128][16]
      for (int x = tid; x < 2048; x += 256)
        bB[x] = b2[(size_t)N1 + (size_t)(x >> 4) * 64 + 16 * jc + (x & 15)];
      float* bC = (float*)(smem + 28672);                // b2C [64][16]
      for (int x = tid; x < 1024; x += 256)
        bC[x] = b2[(size_t)(N1 + N2) + (size_t)(x >> 4) * 64 + 16 * jc + (x & 15)];
    }
    short8 gL0, gH0, gL1, gH1;
    LOADH(0, gL0, gH0);
    LOADH(1, gL1, gH1);
    __syncthreads();

    const int u0B = wid * 32, u0C = wid * 16;
    char* ring = smem + 32768 + wid * 6144;
    const char* gB = BpB + ((size_t)(1024 + u0B * 4 + jc) * 128 + lane) * 16;
    const char* gC = BpB + ((size_t)(1536 + u0C * 4 + jc) * 128 + lane) * 16;
    const unsigned short* sbB = (const unsigned short*)smem + (size_t)u0B * 32 + nl;
    const unsigned short* scC = (const unsigned short*)(smem + 8192) + (size_t)(3 * u0C) * 32 + nl;
    const float* bvB = (const float*)(smem + 20480) + (size_t)u0B * 16 + grp * 4;
    const float* bvC = (const float*)(smem + 28672) + (size_t)u0C * 16 + grp * 4;

    f32x4 aB0 = Zv, aB1 = Zv;
    f32x4 c00 = Zv, c01 = Zv, c02 = Zv, c10 = Zv, c11 = Zv, c12 = Zv;

#define STG_B(K) do { char* dd_ = ring + ((K) % 3) * 2048;                     \
      glds16(gB + (size_t)(K) * 8192, dd_);                                    \
      glds16(gB + (size_t)(K) * 8192 + 1024, dd_ + 1024); } while (0)
#define STG_C(K) do { char* dd_ = ring + ((2 + (K)) % 3) * 2048;               \
      glds16(gC + (size_t)(K) * 8192, dd_);                                    \
      glds16(gC + (size_t)(K) * 8192 + 1024, dd_ + 1024); } while (0)

    STG_B(0); STG_B(1);
#pragma unroll
    for (int t = 0; t < 32; ++t) {
      WAITVM(2);
      if (t < 30) STG_B(t + 2); else STG_C(t - 30);
      const char* rs = ring + (t % 3) * 2048;
      short8 f0 = *(const short8*)(rs + lane * 16);
      short8 f1 = *(const short8*)(rs + 1024 + lane * 16);
      float c0 = bf2f(sbB[t * 32]);
      float c1 = bf2f(sbB[t * 32 + 16]);
      f32x4 bv = *(const f32x4*)(bvB + t * 16);
      f32x4 tt;
      tt = MFMA(f0, gL0, bv); tt = MFMA(f1, gH0, tt); aB0 += c0 * tt;
      tt = MFMA(f0, gL1, bv); tt = MFMA(f1, gH1, tt); aB1 += c1 * tt;
    }
#pragma unroll
    for (int t = 0; t < 16; ++t) {
      if (t < 14)      { WAITVM(2); STG_C(t + 2); }
      else if (t == 14){ WAITVM(2); }
      else             { WAITVM(0); }
      const char* rs = ring + ((2 + t) % 3) * 2048;
      short8 f0 = *(const short8*)(rs + lane * 16);
      short8 f1 = *(const short8*)(rs + 1024 + lane * 16);
      float d00 = bf2f(scC[(3 * t) * 32]);
      float d01 = bf2f(scC[(3 * t) * 32 + 16]);
      float d10 = bf2f(scC[(3 * t + 1) * 32]);
      float d11 = bf2f(scC[(3 * t + 1) * 32 + 16]);
      float d20 = bf2f(scC[(3 * t + 2) * 32]);
      float d21 = bf2f(scC[(3 * t + 2) * 32 + 16]);
      f32x4 bv = *(const f32x4*)(bvC + t * 16);
      f32x4 t0 = MFMA(f0, gL0, bv); t0 = MFMA(f1, gH0, t0);
      f32x4 t1 = MFMA(f0, gL1, bv); t1 = MFMA(f1, gH1, t1);
      c00 += d00 * t0; c01 += d10 * t0; c02 += d20 * t0;
      c10 += d01 * t1; c11 += d11 * t1; c12 += d21 * t1;
    }
#undef STG_B
#undef STG_C
    __syncthreads();
    float* buf = (float*)smem;
    {
      float* bw = buf + wid * 2080;
#pragma unroll
      for (int r = 0; r < 4; ++r) {
        const int w1 = grp * 4 + r;
        bw[nl * 65 + w1]             = aB0[r];
        bw[(16 + nl) * 65 + w1]      = aB1[r];
        bw[nl * 65 + 16 + w1]        = c00[r];
        bw[nl * 65 + 32 + w1]        = c01[r];
        bw[nl * 65 + 48 + w1]        = c02[r];
        bw[(16 + nl) * 65 + 16 + w1] = c10[r];
        bw[(16 + nl) * 65 + 32 + w1] = c11[r];
        bw[(16 + nl) * 65 + 48 + w1] = c12[r];
      }
    }
    __syncthreads();
#pragma unroll
    for (int it = 0; it < 6; ++it) {
      const int p = tid + it * 256;
      const int e = p / 48, rem = p % 48;
      const int w1 = rem / 3, i = rem % 3;
      float tb = buf[e * 65 + w1] + buf[2080 + e * 65 + w1] +
                 buf[4160 + e * 65 + w1] + buf[6240 + e * 65 + w1];
      const int co = 16 + i * 16 + w1;
      float tc = buf[e * 65 + co] + buf[2080 + e * 65 + co] +
                 buf[4160 + e * 65 + co] + buf[6240 + e * 65 + co];
      out[(size_t)(e0 + e) * 320 + 128 + (size_t)(16 * jc + w1) * 3 + i] =
          tb * d2T[(1 + i) * 4096 + e0 + e] + tc;
    }
  }
}

extern "C" void kernel_launch(void* const* d_in, const int* in_sizes, int n_in,
                              void* d_out, int out_size, void* d_ws, size_t ws_size,
                              hipStream_t stream) {
  const float* d1   = (const float*)d_in[0];
  const float* d2   = (const float*)d_in[1];
  const float* wgt  = (const float*)d_in[2];
  const float* W0   = (const float*)d_in[3];
  const float* b0   = (const float*)d_in[4];
  const float* W1   = (const float*)d_in[5];
  const float* b1   = (const float*)d_in[6];
  const float* W2   = (const float*)d_in[7];
  const float* b2   = (const float*)d_in[8];
  const float* bias = (const float*)d_in[9];
  float* out = (float*)d_out;

  char* ws = (char*)d_ws;
  float* H           = (float*)(ws);                         // 1 MiB
  unsigned short* Bp = (unsigned short*)(ws + (1u << 20));   // 4.72 MB
  float* sBg         = (float*)(ws + (8u << 20));            // 2 MB  [128][4096] s1
  float* sDg         = (float*)(ws + (10u << 20));           // 1 MB  [64][4096]  ISQ3*dot12
  float* sCg         = (float*)(ws + (11u << 20));           // 3 MB  [192][4096] v1_i*s2
  float* d2T         = (float*)(ws + (14u << 20));           // 64 KB [4][4096]

  k_prep<<<1440, 256, 0, stream>>>(wgt, W0, b0, W1, b1, W2, d1, d2,
                                   H, Bp, sBg, sDg, sCg, d2T);
  k_main<<<1024, 256, 0, stream>>>(sBg, sDg, sCg, d2T, H, Bp, b2, bias, out);
}